// Round 1
// baseline (777.097 us; speedup 1.0000x reference)
//
#include <hip/hip_runtime.h>
#include <math.h>

#define SEQ   2048
#define BATCH 2
#define NDIM  1024
#define NHEAD 16
#define HDIM  64
#define NB    32

// ---------------------------------------------------------------------------
// GEMM: C[M,1024] = A[M,1024] @ W[1024,1024]^T + bias, M = 4096.
// 128x128 tile, BK=16, 256 threads, 8x8 microtile (columns split tc*4 and
// 64+tc*4 so LDS float4 reads are 2-way conflicted at worst).
// ---------------------------------------------------------------------------
__global__ __launch_bounds__(256) void gemm_xt(const float* __restrict__ A,
                                               const float* __restrict__ W,
                                               const float* __restrict__ bias,
                                               float* __restrict__ C) {
    __shared__ float As[16][132];
    __shared__ float Ws[16][132];

    const int t  = threadIdx.x;
    const int m0 = blockIdx.y * 128;
    const int n0 = blockIdx.x * 128;
    const int tr = t >> 4;   // 0..15 -> rows tr*8 .. tr*8+7
    const int tc = t & 15;   // 0..15 -> cols tc*4..+3 and 64+tc*4..+3

    float acc[8][8];
#pragma unroll
    for (int i = 0; i < 8; ++i)
#pragma unroll
        for (int j = 0; j < 8; ++j) acc[i][j] = 0.f;

    for (int kt = 0; kt < 64; ++kt) {
        const int k0 = kt * 16;
#pragma unroll
        for (int i = 0; i < 8; ++i) {
            const int e = i * 256 + t;
            const int m = e >> 4;
            const int k = e & 15;
            As[k][m] = A[(size_t)(m0 + m) * NDIM + k0 + k];
            Ws[k][m] = W[(size_t)(n0 + m) * NDIM + k0 + k];
        }
        __syncthreads();
#pragma unroll
        for (int k = 0; k < 16; ++k) {
            const float4 a0 = *(const float4*)&As[k][tr * 8];
            const float4 a1 = *(const float4*)&As[k][tr * 8 + 4];
            const float4 w0 = *(const float4*)&Ws[k][tc * 4];
            const float4 w1 = *(const float4*)&Ws[k][tc * 4 + 64];
            const float av[8] = {a0.x, a0.y, a0.z, a0.w, a1.x, a1.y, a1.z, a1.w};
            const float wv[8] = {w0.x, w0.y, w0.z, w0.w, w1.x, w1.y, w1.z, w1.w};
#pragma unroll
            for (int rr = 0; rr < 8; ++rr)
#pragma unroll
                for (int cc = 0; cc < 8; ++cc) acc[rr][cc] += av[rr] * wv[cc];
        }
        __syncthreads();
    }

    // epilogue
    const float4 b0 = *(const float4*)&bias[n0 + tc * 4];
    const float4 b1 = *(const float4*)&bias[n0 + 64 + tc * 4];
#pragma unroll
    for (int rr = 0; rr < 8; ++rr) {
        const size_t row = (size_t)(m0 + tr * 8 + rr);
        float4 c0, c1;
        c0.x = acc[rr][0] + b0.x; c0.y = acc[rr][1] + b0.y;
        c0.z = acc[rr][2] + b0.z; c0.w = acc[rr][3] + b0.w;
        c1.x = acc[rr][4] + b1.x; c1.y = acc[rr][5] + b1.y;
        c1.z = acc[rr][6] + b1.z; c1.w = acc[rr][7] + b1.w;
        *(float4*)&C[row * NDIM + n0 + tc * 4]      = c0;
        *(float4*)&C[row * NDIM + n0 + 64 + tc * 4] = c1;
    }
}

// ---------------------------------------------------------------------------
// Block-sparse (BigBird) attention, fp32, flash-style online softmax.
// grid = (32 query blocks, 16 heads, 2 batch); 256 threads.
// thread t: query row r = t>>2 (0..63), group g = t&3 (16 dims / 16 key cols).
// Q row held in registers; K/V/P tiles staged in LDS (padded stride 68).
// ---------------------------------------------------------------------------
__global__ __launch_bounds__(256) void bigbird_attn(const float* __restrict__ qf,
                                                    const float* __restrict__ kf,
                                                    const float* __restrict__ vf,
                                                    const int* __restrict__ srcb,
                                                    const int* __restrict__ tgtb,
                                                    float* __restrict__ out) {
    __shared__ float Ks[64][68];
    __shared__ float Vs[64][68];
    __shared__ float Ps[64][68];

    const int t = threadIdx.x;
    const int i = blockIdx.x;   // query block
    const int h = blockIdx.y;
    const int b = blockIdx.z;
    const int r = t >> 2;
    const int g = t & 3;

    // allowed key-block bitmask (deduped)
    unsigned mask = 1u | (1u << (NB - 1)) | (1u << i);
    if (i > 0)      mask |= 1u << (i - 1);
    if (i < NB - 1) mask |= 1u << (i + 1);
#pragma unroll
    for (int tt = 0; tt < 3; ++tt)
        if (srcb[tt] == i) mask |= 1u << (tgtb[tt] & 31);

    const size_t headoff = (size_t)b * (SEQ * NDIM) + (size_t)h * (SEQ * HDIM);
    const float* Qh = qf + headoff;
    const float* Kh = kf + headoff;
    const float* Vh = vf + headoff;

    // Q row -> registers (64 floats)
    float q[64];
    {
        const float* qrow = Qh + (size_t)(i * 64 + r) * HDIM;
#pragma unroll
        for (int jj = 0; jj < 16; ++jj) {
            const float4 v = *(const float4*)(qrow + jj * 4);
            q[jj * 4 + 0] = v.x; q[jj * 4 + 1] = v.y;
            q[jj * 4 + 2] = v.z; q[jj * 4 + 3] = v.w;
        }
    }

    float accv[16];
#pragma unroll
    for (int d = 0; d < 16; ++d) accv[d] = 0.f;
    float mrow = -INFINITY, lrow = 0.f;

    for (int kb = 0; kb < NB; ++kb) {
        if (!((mask >> kb) & 1u)) continue;   // uniform across block

        // stage K,V tile rows (thread stages row r, cols g*16..+15)
        {
            const float* krow = Kh + (size_t)(kb * 64 + r) * HDIM + g * 16;
            const float* vrow = Vh + (size_t)(kb * 64 + r) * HDIM + g * 16;
#pragma unroll
            for (int jj = 0; jj < 4; ++jj) {
                *(float4*)&Ks[r][g * 16 + jj * 4] = *(const float4*)(krow + jj * 4);
                *(float4*)&Vs[r][g * 16 + jj * 4] = *(const float4*)(vrow + jj * 4);
            }
        }
        __syncthreads();

        // scores: s[j] = (q . K[g*16+j]) * 0.125
        float s[16];
#pragma unroll
        for (int j = 0; j < 16; ++j) {
            const float* kr = &Ks[g * 16 + j][0];
            float a = 0.f;
#pragma unroll
            for (int dd4 = 0; dd4 < 16; ++dd4) {
                const float4 kv = *(const float4*)(kr + dd4 * 4);
                a += q[dd4 * 4 + 0] * kv.x;
                a += q[dd4 * 4 + 1] * kv.y;
                a += q[dd4 * 4 + 2] * kv.z;
                a += q[dd4 * 4 + 3] * kv.w;
            }
            s[j] = a * 0.125f;
        }

        // row max over the 64 key cols (4 g-lanes share a row)
        float tmax = s[0];
#pragma unroll
        for (int j = 1; j < 16; ++j) tmax = fmaxf(tmax, s[j]);
        tmax = fmaxf(tmax, __shfl_xor(tmax, 1));
        tmax = fmaxf(tmax, __shfl_xor(tmax, 2));

        const float newm = fmaxf(mrow, tmax);
        const float corr = __expf(mrow - newm);   // first tile: exp(-inf)=0
        float psum = 0.f;
#pragma unroll
        for (int j = 0; j < 16; ++j) {
            const float p = __expf(s[j] - newm);
            s[j] = p;
            psum += p;
        }
        psum += __shfl_xor(psum, 1);
        psum += __shfl_xor(psum, 2);
        lrow = lrow * corr + psum;
        mrow = newm;
#pragma unroll
        for (int d = 0; d < 16; ++d) accv[d] *= corr;

        // write P tile
#pragma unroll
        for (int jj = 0; jj < 4; ++jj) {
            float4 p4;
            p4.x = s[jj * 4 + 0]; p4.y = s[jj * 4 + 1];
            p4.z = s[jj * 4 + 2]; p4.w = s[jj * 4 + 3];
            *(float4*)&Ps[r][g * 16 + jj * 4] = p4;
        }
        __syncthreads();

        // PV: accv[d] += sum_kk P[r][kk] * V[kk][g*16+d]
#pragma unroll 8
        for (int kk = 0; kk < 64; ++kk) {
            const float p = Ps[r][kk];
#pragma unroll
            for (int dd4 = 0; dd4 < 4; ++dd4) {
                const float4 vv = *(const float4*)&Vs[kk][g * 16 + dd4 * 4];
                accv[dd4 * 4 + 0] += p * vv.x;
                accv[dd4 * 4 + 1] += p * vv.y;
                accv[dd4 * 4 + 2] += p * vv.z;
                accv[dd4 * 4 + 3] += p * vv.w;
            }
        }
        __syncthreads();   // protect Ks/Vs/Ps before next stage
    }

    const float inv = 1.f / lrow;
    float* orow = out + ((size_t)(b * SEQ + i * 64 + r)) * NDIM + h * HDIM + g * 16;
#pragma unroll
    for (int dd4 = 0; dd4 < 4; ++dd4) {
        float4 o4;
        o4.x = accv[dd4 * 4 + 0] * inv;
        o4.y = accv[dd4 * 4 + 1] * inv;
        o4.z = accv[dd4 * 4 + 2] * inv;
        o4.w = accv[dd4 * 4 + 3] * inv;
        *(float4*)(orow + dd4 * 4) = o4;
    }
}

// ---------------------------------------------------------------------------
extern "C" void kernel_launch(void* const* d_in, const int* in_sizes, int n_in,
                              void* d_out, int out_size, void* d_ws, size_t ws_size,
                              hipStream_t stream) {
    const float* x   = (const float*)d_in[0];
    const float* Wq  = (const float*)d_in[1];
    const float* bq  = (const float*)d_in[2];
    const float* Wk  = (const float*)d_in[3];
    const float* bk  = (const float*)d_in[4];
    const float* Wv  = (const float*)d_in[5];
    const float* bv  = (const float*)d_in[6];
    const float* Wo  = (const float*)d_in[7];
    const float* bo  = (const float*)d_in[8];
    const int* srcb  = (const int*)d_in[9];
    const int* tgtb  = (const int*)d_in[10];
    float* outp      = (float*)d_out;

    float* ws   = (float*)d_ws;
    float* qful = ws;                     // 4096*1024
    float* kful = ws + (size_t)4096 * 1024;
    float* vful = ws + (size_t)4096 * 1024 * 2;
    float* attc = ws + (size_t)4096 * 1024 * 3;

    const dim3 gblk(256), ggrd(8, 32, 1);
    hipLaunchKernelGGL(gemm_xt, ggrd, gblk, 0, stream, x, Wq, bq, qful);
    hipLaunchKernelGGL(gemm_xt, ggrd, gblk, 0, stream, x, Wk, bk, kful);
    hipLaunchKernelGGL(gemm_xt, ggrd, gblk, 0, stream, x, Wv, bv, vful);

    const dim3 ablk(256), agrd(NB, NHEAD, BATCH);
    hipLaunchKernelGGL(bigbird_attn, agrd, ablk, 0, stream,
                       qful, kful, vful, srcb, tgtb, attc);

    hipLaunchKernelGGL(gemm_xt, ggrd, gblk, 0, stream, attc, Wo, bo, outp);

    (void)in_sizes; (void)n_in; (void)out_size; (void)ws_size;
}

// Round 3
// 107.157 us; speedup vs baseline: 7.2519x; 7.2519x over previous
//
#include <hip/hip_runtime.h>
#include <math.h>

typedef __attribute__((ext_vector_type(8))) short short8;
typedef __attribute__((ext_vector_type(4))) float f32x4;

#define SEQ 2048
#define NB  32

__device__ __forceinline__ unsigned short f2bf(float f) {
    unsigned u = __float_as_uint(f);
    u = (u + 0x7FFFu + ((u >> 16) & 1u)) >> 16;   // RNE
    return (unsigned short)u;
}

// ---------------------------------------------------------------------------
// fp32 -> bf16 (RNE), 8 elems/thread, grid-stride
// ---------------------------------------------------------------------------
__global__ __launch_bounds__(256) void cvt_bf16(const float* __restrict__ in,
                                                unsigned short* __restrict__ out, int n8) {
    int i = blockIdx.x * 256 + threadIdx.x;
    const int stride = gridDim.x * 256;
    for (; i < n8; i += stride) {
        const float4 a = ((const float4*)in)[i * 2];
        const float4 b = ((const float4*)in)[i * 2 + 1];
        uint4 o;
        o.x = f2bf(a.x) | ((unsigned)f2bf(a.y) << 16);
        o.y = f2bf(a.z) | ((unsigned)f2bf(a.w) << 16);
        o.z = f2bf(b.x) | ((unsigned)f2bf(b.y) << 16);
        o.w = f2bf(b.z) | ((unsigned)f2bf(b.w) << 16);
        ((uint4*)out)[i] = o;
    }
}

// ---------------------------------------------------------------------------
// bf16 MFMA GEMM: C[M,1024] = A[M,1024] @ W[1024,1024]^T + bias
// 128x128 tile, BK=32, 256 thr (4 waves 2x2, each 64x64 = 4x4 frags of 16x16).
// which = blockIdx.x>>3 selects W/bias/out (QKV fused); BF16OUT: bf16 vs f32.
// ---------------------------------------------------------------------------
template <int BF16OUT>
__global__ __launch_bounds__(256) void gemm_bt(const unsigned short* __restrict__ A,
                                               const unsigned short* __restrict__ Wall,
                                               const float* __restrict__ b0,
                                               const float* __restrict__ b1,
                                               const float* __restrict__ b2,
                                               unsigned short* __restrict__ outb,
                                               float* __restrict__ outf) {
    __shared__ __align__(16) unsigned short As[128 * 32];
    __shared__ __align__(16) unsigned short Bs[128 * 32];

    const int t = threadIdx.x;
    const int w = t >> 6, l = t & 63;
    const int which = blockIdx.x >> 3;
    const int n0 = (blockIdx.x & 7) * 128;
    const int m0 = blockIdx.y * 128;
    const unsigned short* W = Wall + (size_t)which * (1024ull * 1024);
    const float* bias = (which == 0) ? b0 : (which == 1) ? b1 : b2;

    const int wr = (w >> 1) * 64, wc = (w & 1) * 64;
    f32x4 acc[4][4];
#pragma unroll
    for (int i = 0; i < 4; ++i)
#pragma unroll
        for (int j = 0; j < 4; ++j) acc[i][j] = f32x4{0.f, 0.f, 0.f, 0.f};

    const int srow = t >> 2;          // 0..63
    const int skk = (t & 3) * 8;      // 0,8,16,24

    // prefetch k-tile 0
    uint4 a0 = *(const uint4*)&A[(size_t)(m0 + srow) * 1024 + skk];
    uint4 a1 = *(const uint4*)&A[(size_t)(m0 + 64 + srow) * 1024 + skk];
    uint4 w0 = *(const uint4*)&W[(size_t)(n0 + srow) * 1024 + skk];
    uint4 w1 = *(const uint4*)&W[(size_t)(n0 + 64 + srow) * 1024 + skk];

    for (int kt = 0; kt < 32; ++kt) {
        __syncthreads();   // previous iteration's frag reads done
        *(uint4*)&As[srow * 32 + skk] = a0;
        *(uint4*)&As[(64 + srow) * 32 + skk] = a1;
        *(uint4*)&Bs[srow * 32 + skk] = w0;
        *(uint4*)&Bs[(64 + srow) * 32 + skk] = w1;
        __syncthreads();

        if (kt + 1 < 32) {   // issue next tile's loads; consumed next iteration
            const int k0 = (kt + 1) * 32;
            a0 = *(const uint4*)&A[(size_t)(m0 + srow) * 1024 + k0 + skk];
            a1 = *(const uint4*)&A[(size_t)(m0 + 64 + srow) * 1024 + k0 + skk];
            w0 = *(const uint4*)&W[(size_t)(n0 + srow) * 1024 + k0 + skk];
            w1 = *(const uint4*)&W[(size_t)(n0 + 64 + srow) * 1024 + k0 + skk];
        }

        short8 af[4], bf[4];
#pragma unroll
        for (int mi = 0; mi < 4; ++mi)
            af[mi] = *(const short8*)&As[(wr + mi * 16 + (l & 15)) * 32 + (l >> 4) * 8];
#pragma unroll
        for (int ni = 0; ni < 4; ++ni)
            bf[ni] = *(const short8*)&Bs[(wc + ni * 16 + (l & 15)) * 32 + (l >> 4) * 8];
#pragma unroll
        for (int mi = 0; mi < 4; ++mi)
#pragma unroll
            for (int ni = 0; ni < 4; ++ni)
                acc[mi][ni] = __builtin_amdgcn_mfma_f32_16x16x32_bf16(af[mi], bf[ni],
                                                                      acc[mi][ni], 0, 0, 0);
    }

    const int g = l >> 4, c = l & 15;
#pragma unroll
    for (int ni = 0; ni < 4; ++ni) {
        const int n = n0 + wc + ni * 16 + c;
        const float bv = bias[n];
#pragma unroll
        for (int mi = 0; mi < 4; ++mi) {
#pragma unroll
            for (int j = 0; j < 4; ++j) {
                const size_t m = (size_t)(m0 + wr + mi * 16 + g * 4 + j);
                const float v = acc[mi][ni][j] + bv;
                if (BF16OUT)
                    (outb + (size_t)which * (4096ull * 1024))[m * 1024 + n] = f2bf(v);
                else
                    outf[m * 1024 + n] = v;
            }
        }
    }
}

// ---------------------------------------------------------------------------
// V transpose: per (b,h) [2048][64] -> [64][2048] (bf16), 64x64 LDS tiles.
// ---------------------------------------------------------------------------
__global__ __launch_bounds__(256) void transpose_v(const unsigned short* __restrict__ v,
                                                   unsigned short* __restrict__ vt) {
    __shared__ __align__(16) unsigned short L[64][72];
    const int t = threadIdx.x;
    const int st = blockIdx.x;   // s tile 0..31
    const int ht = blockIdx.y;   // head 0..15
    const int b = blockIdx.z;
    {
        const int r = t >> 2, cs = t & 3;
        const unsigned short* src =
            v + (size_t)(b * 16 + ht) * (SEQ * 64) + (size_t)(st * 64 + r) * 64 + cs * 16;
        *(uint4*)&L[r][cs * 16] = *(const uint4*)src;
        *(uint4*)&L[r][cs * 16 + 8] = *(const uint4*)(src + 8);
    }
    __syncthreads();
    {
        const int dr = t >> 2, ss = t & 3;
        unsigned short tmp[16];
#pragma unroll
        for (int e = 0; e < 16; ++e) tmp[e] = L[ss * 16 + e][dr];
        unsigned short* dst =
            vt + (size_t)(b * 16 + ht) * (SEQ * 64) + (size_t)dr * SEQ + st * 64 + ss * 16;
        *(uint4*)dst = *(uint4*)&tmp[0];
        *(uint4*)(dst + 8) = *(uint4*)&tmp[8];
    }
}

// ---------------------------------------------------------------------------
// BigBird MFMA attention (bf16 in, bf16 out), swapped-QK^T flash style.
// grid (32 qblk, 16 h, 2 b), 256 thr = 4 waves; wave w owns 16 q-rows.
// S^T = K·Q^T  (C: col=q=l&15, row=key) -> softmax in-lane + 2 shfl_xor.
// P -> per-wave LDS bf16 [q][key];  O^T = V^T·P^T  (V^T staged from vt).
// ---------------------------------------------------------------------------
__global__ __launch_bounds__(256) void attn_mfma(const unsigned short* __restrict__ qb_,
                                                 const unsigned short* __restrict__ kb_,
                                                 const unsigned short* __restrict__ vtb_,
                                                 const int* __restrict__ srcb,
                                                 const int* __restrict__ tgtb,
                                                 unsigned short* __restrict__ outb) {
    __shared__ __align__(16) unsigned short Ks[64 * 72];
    __shared__ __align__(16) unsigned short Vs[64 * 72];   // holds V^T tile [d][key]
    __shared__ __align__(16) unsigned short Ps[4][16 * 72];

    const int t = threadIdx.x, w = t >> 6, l = t & 63;
    const int qi = blockIdx.x, h = blockIdx.y, b = blockIdx.z;
    const int g = l >> 4, c = l & 15;

    unsigned mask = 1u | (1u << (NB - 1)) | (1u << qi);
    if (qi > 0) mask |= 1u << (qi - 1);
    if (qi < NB - 1) mask |= 1u << (qi + 1);
#pragma unroll
    for (int tt = 0; tt < 3; ++tt)
        if (srcb[tt] == qi) mask |= 1u << (tgtb[tt] & 31);

    const size_t ho = (size_t)(b * 16 + h) * (SEQ * 64);
    const unsigned short* Q = qb_ + ho;
    const unsigned short* K = kb_ + ho;
    const unsigned short* VT = vtb_ + ho;

    // Q^T B-fragments, held in regs: q-row = qi*64 + w*16 + c, d = ks*32 + g*8 ..+7
    short8 qf[2];
    {
        const unsigned short* qrow = Q + (size_t)(qi * 64 + w * 16 + c) * 64;
        qf[0] = *(const short8*)(qrow + g * 8);
        qf[1] = *(const short8*)(qrow + 32 + g * 8);
    }

    f32x4 oacc[4];
#pragma unroll
    for (int d = 0; d < 4; ++d) oacc[d] = f32x4{0.f, 0.f, 0.f, 0.f};
    float mrun = -INFINITY, lsum = 0.f;

    const int sr = t >> 2, sc = (t & 3) * 16;   // staging coords

    for (int kb = 0; kb < NB; ++kb) {
        if (!((mask >> kb) & 1u)) continue;

        // issue stage loads (regs) before the barrier — latency hides under it
        const unsigned short* ksrc = K + (size_t)(kb * 64 + sr) * 64 + sc;
        const unsigned short* vsrc = VT + (size_t)sr * SEQ + kb * 64 + sc;
        uint4 k0 = *(const uint4*)ksrc, k1 = *(const uint4*)(ksrc + 8);
        uint4 v0 = *(const uint4*)vsrc, v1 = *(const uint4*)(vsrc + 8);

        __syncthreads();   // all waves done with previous tile
        *(uint4*)&Ks[sr * 72 + sc] = k0;
        *(uint4*)&Ks[sr * 72 + sc + 8] = k1;
        *(uint4*)&Vs[sr * 72 + sc] = v0;
        *(uint4*)&Vs[sr * 72 + sc + 8] = v1;
        __syncthreads();

        // S^T = K·Q^T : 4 key-tiles x 2 k-steps
        f32x4 sacc[4];
#pragma unroll
        for (int kt = 0; kt < 4; ++kt) sacc[kt] = f32x4{0.f, 0.f, 0.f, 0.f};
#pragma unroll
        for (int kt = 0; kt < 4; ++kt) {
#pragma unroll
            for (int ks = 0; ks < 2; ++ks) {
                const short8 ka = *(const short8*)&Ks[(kt * 16 + c) * 72 + ks * 32 + g * 8];
                sacc[kt] = __builtin_amdgcn_mfma_f32_16x16x32_bf16(ka, qf[ks], sacc[kt], 0, 0, 0);
            }
        }

        // online softmax; lane's 16 scores all belong to q-col c (keys kt*16+g*4+j)
        float sv[16];
        float tmax = -INFINITY;
#pragma unroll
        for (int kt = 0; kt < 4; ++kt)
#pragma unroll
            for (int j = 0; j < 4; ++j) {
                const float x = sacc[kt][j] * 0.125f;
                sv[kt * 4 + j] = x;
                tmax = fmaxf(tmax, x);
            }
        tmax = fmaxf(tmax, __shfl_xor(tmax, 16));
        tmax = fmaxf(tmax, __shfl_xor(tmax, 32));
        const float newm = fmaxf(mrun, tmax);
        const float corr = __expf(mrun - newm);
        float ps = 0.f;
#pragma unroll
        for (int e = 0; e < 16; ++e) {
            const float p = __expf(sv[e] - newm);
            sv[e] = p;
            ps += p;
        }
        ps += __shfl_xor(ps, 16);
        ps += __shfl_xor(ps, 32);
        lsum = lsum * corr + ps;
        mrun = newm;
#pragma unroll
        for (int d = 0; d < 4; ++d)
#pragma unroll
            for (int j = 0; j < 4; ++j) oacc[d][j] *= corr;

        // P (bf16) -> per-wave LDS [q=c][key]
        unsigned short* pw = &Ps[w][c * 72];
#pragma unroll
        for (int kt = 0; kt < 4; ++kt) {
            uint2 pk;
            pk.x = f2bf(sv[kt * 4 + 0]) | ((unsigned)f2bf(sv[kt * 4 + 1]) << 16);
            pk.y = f2bf(sv[kt * 4 + 2]) | ((unsigned)f2bf(sv[kt * 4 + 3]) << 16);
            *(uint2*)&pw[kt * 16 + g * 4] = pk;
        }
        asm volatile("s_waitcnt lgkmcnt(0)" ::: "memory");   // same-wave LDS RAW
        __builtin_amdgcn_sched_barrier(0);                   // rule #18 hygiene

        // O^T += V^T·P^T : 4 d-tiles x 2 k-steps (k = key)
#pragma unroll
        for (int ks = 0; ks < 2; ++ks) {
            const short8 pb = *(const short8*)&Ps[w][c * 72 + ks * 32 + g * 8];
#pragma unroll
            for (int dt = 0; dt < 4; ++dt) {
                const short8 va = *(const short8*)&Vs[(dt * 16 + c) * 72 + ks * 32 + g * 8];
                oacc[dt] = __builtin_amdgcn_mfma_f32_16x16x32_bf16(va, pb, oacc[dt], 0, 0, 0);
            }
        }
    }

    // epilogue: out[b*2048 + qi*64 + q][h*64 + d], lane: q=c, d=dt*16+g*4+j
    const float inv = 1.f / lsum;
    unsigned short* orow = outb + (size_t)(b * SEQ + qi * 64 + w * 16 + c) * 1024 + h * 64;
#pragma unroll
    for (int dt = 0; dt < 4; ++dt)
#pragma unroll
        for (int j = 0; j < 4; ++j)
            orow[dt * 16 + g * 4 + j] = f2bf(oacc[dt][j] * inv);
}

// ---------------------------------------------------------------------------
extern "C" void kernel_launch(void* const* d_in, const int* in_sizes, int n_in,
                              void* d_out, int out_size, void* d_ws, size_t ws_size,
                              hipStream_t stream) {
    const float* x  = (const float*)d_in[0];
    const float* Wq = (const float*)d_in[1];
    const float* bq = (const float*)d_in[2];
    const float* Wk = (const float*)d_in[3];
    const float* bk = (const float*)d_in[4];
    const float* Wv = (const float*)d_in[5];
    const float* bv = (const float*)d_in[6];
    const float* Wo = (const float*)d_in[7];
    const float* bo = (const float*)d_in[8];
    const int* srcb = (const int*)d_in[9];
    const int* tgtb = (const int*)d_in[10];

    unsigned short* wsu = (unsigned short*)d_ws;
    // layout (shorts): no overlaps (round-1 bug: attbf collided with vtbf[batch1])
    unsigned short* xbf   = wsu;                      // [0,        4194304)
    unsigned short* wqkv  = wsu + 4194304ull;         // [4194304,  7340032)
    unsigned short* wobf  = wsu + 7340032ull;         // [7340032,  8388608)
    unsigned short* qkvbf = wsu + 8388608ull;         // [8388608,  20971520)
    unsigned short* vtbf  = wsu + 20971520ull;        // [20971520, 25165824)  2*16*64*2048
    unsigned short* attbf = wsu + 25165824ull;        // [25165824, 29360128)

    hipLaunchKernelGGL(cvt_bf16, dim3(1024), dim3(256), 0, stream, x, xbf, 524288);
    hipLaunchKernelGGL(cvt_bf16, dim3(512), dim3(256), 0, stream, Wq, wqkv, 131072);
    hipLaunchKernelGGL(cvt_bf16, dim3(512), dim3(256), 0, stream, Wk, wqkv + 1048576ull, 131072);
    hipLaunchKernelGGL(cvt_bf16, dim3(512), dim3(256), 0, stream, Wv, wqkv + 2097152ull, 131072);
    hipLaunchKernelGGL(cvt_bf16, dim3(512), dim3(256), 0, stream, Wo, wobf, 131072);

    // fused QKV GEMM (which = blockIdx.x>>3)
    hipLaunchKernelGGL((gemm_bt<1>), dim3(24, 32), dim3(256), 0, stream,
                       xbf, wqkv, bq, bk, bv, qkvbf, (float*)nullptr);

    hipLaunchKernelGGL(transpose_v, dim3(32, 16, 2), dim3(256), 0, stream,
                       qkvbf + 2ull * 4194304ull, vtbf);

    hipLaunchKernelGGL(attn_mfma, dim3(32, 16, 2), dim3(256), 0, stream,
                       qkvbf, qkvbf + 4194304ull, vtbf, srcb, tgtb, attbf);

    // O projection -> fp32 d_out (grid.x=8 -> which=0)
    hipLaunchKernelGGL((gemm_bt<0>), dim3(8, 32), dim3(256), 0, stream,
                       attbf, wobf, bo, bo, bo, (unsigned short*)nullptr, (float*)d_out);

    (void)in_sizes; (void)n_in; (void)out_size; (void)ws_size;
}

// Round 6
// 97.533 us; speedup vs baseline: 7.9675x; 1.0987x over previous
//
#include <hip/hip_runtime.h>
#include <math.h>

typedef __attribute__((ext_vector_type(8))) short short8;
typedef __attribute__((ext_vector_type(4))) float f32x4;

#define SEQ 2048
#define NB  32

__device__ __forceinline__ unsigned short f2bf(float f) {
    unsigned u = __float_as_uint(f);
    u = (u + 0x7FFFu + ((u >> 16) & 1u)) >> 16;   // RNE
    return (unsigned short)u;
}

// async global->LDS, 16B per lane; LDS dest = wave-uniform base + lane*16
__device__ __forceinline__ void gload16(const unsigned short* g, unsigned short* l) {
    __builtin_amdgcn_global_load_lds(
        (__attribute__((address_space(1))) void*)(void*)(g),
        (__attribute__((address_space(3))) void*)(l), 16, 0, 0);
}

// ---------------------------------------------------------------------------
// fp32 -> bf16 (RNE), 8 elems/thread, grid-stride
// ---------------------------------------------------------------------------
__global__ __launch_bounds__(256) void cvt_bf16(const float* __restrict__ in,
                                                unsigned short* __restrict__ out, int n8) {
    int i = blockIdx.x * 256 + threadIdx.x;
    const int stride = gridDim.x * 256;
    for (; i < n8; i += stride) {
        const float4 a = ((const float4*)in)[i * 2];
        const float4 b = ((const float4*)in)[i * 2 + 1];
        uint4 o;
        o.x = f2bf(a.x) | ((unsigned)f2bf(a.y) << 16);
        o.y = f2bf(a.z) | ((unsigned)f2bf(a.w) << 16);
        o.z = f2bf(b.x) | ((unsigned)f2bf(b.y) << 16);
        o.w = f2bf(b.z) | ((unsigned)f2bf(b.w) << 16);
        ((uint4*)out)[i] = o;
    }
}

// 4 weight matrices in one dispatch (blockIdx.y selects)
__global__ __launch_bounds__(256) void cvt_w4(const float* __restrict__ w0,
                                              const float* __restrict__ w1,
                                              const float* __restrict__ w2,
                                              const float* __restrict__ w3,
                                              unsigned short* __restrict__ o0,
                                              unsigned short* __restrict__ o1,
                                              unsigned short* __restrict__ o2,
                                              unsigned short* __restrict__ o3) {
    const int which = blockIdx.y;
    const float* in = (which == 0) ? w0 : (which == 1) ? w1 : (which == 2) ? w2 : w3;
    unsigned short* out = (which == 0) ? o0 : (which == 1) ? o1 : (which == 2) ? o2 : o3;
    int i = blockIdx.x * 256 + threadIdx.x;
    const int stride = gridDim.x * 256;
    for (; i < 131072; i += stride) {
        const float4 a = ((const float4*)in)[i * 2];
        const float4 b = ((const float4*)in)[i * 2 + 1];
        uint4 o;
        o.x = f2bf(a.x) | ((unsigned)f2bf(a.y) << 16);
        o.y = f2bf(a.z) | ((unsigned)f2bf(a.w) << 16);
        o.z = f2bf(b.x) | ((unsigned)f2bf(b.y) << 16);
        o.w = f2bf(b.z) | ((unsigned)f2bf(b.w) << 16);
        ((uint4*)out)[i] = o;
    }
}

// ---------------------------------------------------------------------------
// bf16 MFMA GEMM: C[M,1024] = A[M,1024] @ W[1024,1024]^T + bias, M=4096.
// BM=128, BK=32, 256 thr. global_load_lds staging (linear LDS, 16B/lane).
// BN=128: 4 waves 2x2 (64x64 each), grid.x = 8*nW, which=bx>>3 (QKV fused).
// BN=64:  4 waves 4x1 (32x64 each), grid.x = 16, which=0 (O projection).
// BF16OUT: bf16 (outb) vs f32 (outf).
// NOTE (round-3 lesson): head split is a .view — head h = GEMM ROWS
// h*128..h*128+127 per batch, NOT column slices. Any fused layout change
// must respect s' = (s%128)*16 + n/64, d = n%64.
// ---------------------------------------------------------------------------
template <int BF16OUT, int BN>
__global__ __launch_bounds__(256) void gemm_bt(const unsigned short* __restrict__ A,
                                               const unsigned short* __restrict__ Wall,
                                               const float* __restrict__ b0,
                                               const float* __restrict__ b1,
                                               const float* __restrict__ b2,
                                               unsigned short* __restrict__ outb,
                                               float* __restrict__ outf) {
    constexpr int MI = (BN == 128) ? 4 : 2;
    constexpr int NI = 4;
    __shared__ __align__(16) unsigned short As[128 * 32];
    __shared__ __align__(16) unsigned short Bs[BN * 32];

    const int t = threadIdx.x;
    const int w = t >> 6, l = t & 63;
    const int bx = blockIdx.x;
    const int which = (BN == 128) ? (bx >> 3) : 0;
    const int n0 = (BN == 128) ? (bx & 7) * 128 : bx * 64;
    const int m0 = blockIdx.y * 128;
    const unsigned short* W = Wall + (size_t)which * (1024ull * 1024);
    const float* bias = (which == 0) ? b0 : (which == 1) ? b1 : b2;

    const int wr = (BN == 128) ? (w >> 1) * 64 : w * 32;
    const int wc = (BN == 128) ? (w & 1) * 64 : 0;

    f32x4 acc[MI][NI];
#pragma unroll
    for (int i = 0; i < MI; ++i)
#pragma unroll
        for (int j = 0; j < NI; ++j) acc[i][j] = f32x4{0.f, 0.f, 0.f, 0.f};

    // staging: per wave, A rows w*32..+31 (2 chunks of 16 rows); B likewise
    const unsigned short* Ag = A + (size_t)(m0 + w * 32 + (l >> 2)) * 1024 + (l & 3) * 8;
    const unsigned short* Wg =
        W + (size_t)(n0 + ((BN == 128) ? w * 32 : w * 16) + (l >> 2)) * 1024 + (l & 3) * 8;
    unsigned short* AsW = As + w * 1024;                          // 2048 B / wave
    unsigned short* BsW = Bs + ((BN == 128) ? w * 1024 : w * 512);

    for (int kt = 0; kt < 32; ++kt) {
        const int k0 = kt * 32;
        __syncthreads();   // previous iteration's frag reads done
        gload16(Ag + k0, AsW);
        gload16(Ag + k0 + 16 * 1024, AsW + 512);
        gload16(Wg + k0, BsW);
        if (BN == 128) gload16(Wg + k0 + 16 * 1024, BsW + 512);
        __syncthreads();   // vmcnt(0) drain -> LDS visible

        short8 af[MI], bfr[NI];
#pragma unroll
        for (int mi = 0; mi < MI; ++mi)
            af[mi] = *(const short8*)&As[(wr + mi * 16 + (l & 15)) * 32 + (l >> 4) * 8];
#pragma unroll
        for (int ni = 0; ni < NI; ++ni)
            bfr[ni] = *(const short8*)&Bs[(wc + ni * 16 + (l & 15)) * 32 + (l >> 4) * 8];
#pragma unroll
        for (int mi = 0; mi < MI; ++mi)
#pragma unroll
            for (int ni = 0; ni < NI; ++ni)
                acc[mi][ni] = __builtin_amdgcn_mfma_f32_16x16x32_bf16(af[mi], bfr[ni],
                                                                      acc[mi][ni], 0, 0, 0);
    }

    const int g = l >> 4, c = l & 15;
#pragma unroll
    for (int ni = 0; ni < NI; ++ni) {
        const int n = n0 + wc + ni * 16 + c;
        const float bv = bias[n];
#pragma unroll
        for (int mi = 0; mi < MI; ++mi) {
#pragma unroll
            for (int j = 0; j < 4; ++j) {
                const size_t m = (size_t)(m0 + wr + mi * 16 + g * 4 + j);
                const float v = acc[mi][ni][j] + bv;
                if (BF16OUT)
                    (outb + (size_t)which * (4096ull * 1024))[m * 1024 + n] = f2bf(v);
                else
                    outf[m * 1024 + n] = v;
            }
        }
    }
}

// ---------------------------------------------------------------------------
// V transpose: per (b,h) [2048][64] -> [64][2048] (bf16), 64x64 LDS tiles.
// (proven in rounds 2-3; reads the flat V pane as the [B][H][S][D] view)
// ---------------------------------------------------------------------------
__global__ __launch_bounds__(256) void transpose_v(const unsigned short* __restrict__ v,
                                                   unsigned short* __restrict__ vt) {
    __shared__ __align__(16) unsigned short L[64][72];
    const int t = threadIdx.x;
    const int st = blockIdx.x;   // s tile 0..31
    const int ht = blockIdx.y;   // head 0..15
    const int b = blockIdx.z;
    {
        const int r = t >> 2, cs = t & 3;
        const unsigned short* src =
            v + (size_t)(b * 16 + ht) * (SEQ * 64) + (size_t)(st * 64 + r) * 64 + cs * 16;
        *(uint4*)&L[r][cs * 16] = *(const uint4*)src;
        *(uint4*)&L[r][cs * 16 + 8] = *(const uint4*)(src + 8);
    }
    __syncthreads();
    {
        const int dr = t >> 2, ss = t & 3;
        unsigned short tmp[16];
#pragma unroll
        for (int e = 0; e < 16; ++e) tmp[e] = L[ss * 16 + e][dr];
        unsigned short* dst =
            vt + (size_t)(b * 16 + ht) * (SEQ * 64) + (size_t)dr * SEQ + st * 64 + ss * 16;
        *(uint4*)dst = *(uint4*)&tmp[0];
        *(uint4*)(dst + 8) = *(uint4*)&tmp[8];
    }
}

// ---------------------------------------------------------------------------
// BigBird MFMA attention (bf16 in, bf16 out), swapped-QK^T flash style.
// grid (32 qblk, 16 h, 2 b), 256 thr = 4 waves; wave w owns 16 q-rows.
// S^T = K·Q^T -> softmax in-lane + 2 shfl_xor;  O^T = V^T·P^T.
// ---------------------------------------------------------------------------
__global__ __launch_bounds__(256) void attn_mfma(const unsigned short* __restrict__ qb_,
                                                 const unsigned short* __restrict__ kb_,
                                                 const unsigned short* __restrict__ vtb_,
                                                 const int* __restrict__ srcb,
                                                 const int* __restrict__ tgtb,
                                                 unsigned short* __restrict__ outb) {
    __shared__ __align__(16) unsigned short Ks[64 * 72];
    __shared__ __align__(16) unsigned short Vs[64 * 72];   // V^T tile [d][key]
    __shared__ __align__(16) unsigned short Ps[4][16 * 72];

    const int t = threadIdx.x, w = t >> 6, l = t & 63;
    const int qi = blockIdx.x, h = blockIdx.y, b = blockIdx.z;
    const int g = l >> 4, c = l & 15;

    unsigned mask = 1u | (1u << (NB - 1)) | (1u << qi);
    if (qi > 0) mask |= 1u << (qi - 1);
    if (qi < NB - 1) mask |= 1u << (qi + 1);
#pragma unroll
    for (int tt = 0; tt < 3; ++tt)
        if (srcb[tt] == qi) mask |= 1u << (tgtb[tt] & 31);

    const size_t ho = (size_t)(b * 16 + h) * (SEQ * 64);
    const unsigned short* Q = qb_ + ho;
    const unsigned short* K = kb_ + ho;
    const unsigned short* VT = vtb_ + ho;

    short8 qf[2];
    {
        const unsigned short* qrow = Q + (size_t)(qi * 64 + w * 16 + c) * 64;
        qf[0] = *(const short8*)(qrow + g * 8);
        qf[1] = *(const short8*)(qrow + 32 + g * 8);
    }

    f32x4 oacc[4];
#pragma unroll
    for (int d = 0; d < 4; ++d) oacc[d] = f32x4{0.f, 0.f, 0.f, 0.f};
    float mrun = -INFINITY, lsum = 0.f;

    const int sr = t >> 2, sc = (t & 3) * 16;

    for (int kb = 0; kb < NB; ++kb) {
        if (!((mask >> kb) & 1u)) continue;

        const unsigned short* ksrc = K + (size_t)(kb * 64 + sr) * 64 + sc;
        const unsigned short* vsrc = VT + (size_t)sr * SEQ + kb * 64 + sc;
        uint4 k0 = *(const uint4*)ksrc, k1 = *(const uint4*)(ksrc + 8);
        uint4 v0 = *(const uint4*)vsrc, v1 = *(const uint4*)(vsrc + 8);

        __syncthreads();
        *(uint4*)&Ks[sr * 72 + sc] = k0;
        *(uint4*)&Ks[sr * 72 + sc + 8] = k1;
        *(uint4*)&Vs[sr * 72 + sc] = v0;
        *(uint4*)&Vs[sr * 72 + sc + 8] = v1;
        __syncthreads();

        f32x4 sacc[4];
#pragma unroll
        for (int kt = 0; kt < 4; ++kt) sacc[kt] = f32x4{0.f, 0.f, 0.f, 0.f};
#pragma unroll
        for (int kt = 0; kt < 4; ++kt) {
#pragma unroll
            for (int ks = 0; ks < 2; ++ks) {
                const short8 ka = *(const short8*)&Ks[(kt * 16 + c) * 72 + ks * 32 + g * 8];
                sacc[kt] = __builtin_amdgcn_mfma_f32_16x16x32_bf16(ka, qf[ks], sacc[kt], 0, 0, 0);
            }
        }

        float sv[16];
        float tmax = -INFINITY;
#pragma unroll
        for (int kt = 0; kt < 4; ++kt)
#pragma unroll
            for (int j = 0; j < 4; ++j) {
                const float x = sacc[kt][j] * 0.125f;
                sv[kt * 4 + j] = x;
                tmax = fmaxf(tmax, x);
            }
        tmax = fmaxf(tmax, __shfl_xor(tmax, 16));
        tmax = fmaxf(tmax, __shfl_xor(tmax, 32));
        const float newm = fmaxf(mrun, tmax);
        const float corr = __expf(mrun - newm);
        float ps = 0.f;
#pragma unroll
        for (int e = 0; e < 16; ++e) {
            const float p = __expf(sv[e] - newm);
            sv[e] = p;
            ps += p;
        }
        ps += __shfl_xor(ps, 16);
        ps += __shfl_xor(ps, 32);
        lsum = lsum * corr + ps;
        mrun = newm;
#pragma unroll
        for (int d = 0; d < 4; ++d)
#pragma unroll
            for (int j = 0; j < 4; ++j) oacc[d][j] *= corr;

        unsigned short* pw = &Ps[w][c * 72];
#pragma unroll
        for (int kt = 0; kt < 4; ++kt) {
            uint2 pk;
            pk.x = f2bf(sv[kt * 4 + 0]) | ((unsigned)f2bf(sv[kt * 4 + 1]) << 16);
            pk.y = f2bf(sv[kt * 4 + 2]) | ((unsigned)f2bf(sv[kt * 4 + 3]) << 16);
            *(uint2*)&pw[kt * 16 + g * 4] = pk;
        }
        asm volatile("s_waitcnt lgkmcnt(0)" ::: "memory");   // same-wave LDS RAW
        __builtin_amdgcn_sched_barrier(0);

#pragma unroll
        for (int ks = 0; ks < 2; ++ks) {
            const short8 pb = *(const short8*)&Ps[w][c * 72 + ks * 32 + g * 8];
#pragma unroll
            for (int dt = 0; dt < 4; ++dt) {
                const short8 va = *(const short8*)&Vs[(dt * 16 + c) * 72 + ks * 32 + g * 8];
                oacc[dt] = __builtin_amdgcn_mfma_f32_16x16x32_bf16(va, pb, oacc[dt], 0, 0, 0);
            }
        }
    }

    const float inv = 1.f / lsum;
    unsigned short* orow = outb + (size_t)(b * SEQ + qi * 64 + w * 16 + c) * 1024 + h * 64;
#pragma unroll
    for (int dt = 0; dt < 4; ++dt)
#pragma unroll
        for (int j = 0; j < 4; ++j)
            orow[dt * 16 + g * 4 + j] = f2bf(oacc[dt][j] * inv);
}

// ---------------------------------------------------------------------------
extern "C" void kernel_launch(void* const* d_in, const int* in_sizes, int n_in,
                              void* d_out, int out_size, void* d_ws, size_t ws_size,
                              hipStream_t stream) {
    const float* x  = (const float*)d_in[0];
    const float* Wq = (const float*)d_in[1];
    const float* bq = (const float*)d_in[2];
    const float* Wk = (const float*)d_in[3];
    const float* bk = (const float*)d_in[4];
    const float* Wv = (const float*)d_in[5];
    const float* bv = (const float*)d_in[6];
    const float* Wo = (const float*)d_in[7];
    const float* bo = (const float*)d_in[8];
    const int* srcb = (const int*)d_in[9];
    const int* tgtb = (const int*)d_in[10];

    unsigned short* wsu = (unsigned short*)d_ws;
    unsigned short* xbf   = wsu;                      // [0,        4194304)
    unsigned short* wqkv  = wsu + 4194304ull;         // [4194304,  7340032)
    unsigned short* wobf  = wsu + 7340032ull;         // [7340032,  8388608)
    unsigned short* qkvbf = wsu + 8388608ull;         // [8388608,  20971520) Q,K,V panes
    unsigned short* vtbf  = wsu + 20971520ull;        // [20971520, 25165824) V^T 2*16*64*2048
    unsigned short* attbf = wsu + 25165824ull;        // [25165824, 29360128)

    hipLaunchKernelGGL(cvt_bf16, dim3(1024), dim3(256), 0, stream, x, xbf, 524288);
    hipLaunchKernelGGL(cvt_w4, dim3(512, 4), dim3(256), 0, stream,
                       Wq, Wk, Wv, Wo,
                       wqkv, wqkv + 1048576ull, wqkv + 2097152ull, wobf);

    // fused QKV GEMM (which = blockIdx.x>>3), plain [m][n] outputs
    hipLaunchKernelGGL((gemm_bt<1, 128>), dim3(24, 32), dim3(256), 0, stream,
                       xbf, wqkv, bq, bk, bv, qkvbf, (float*)nullptr);

    hipLaunchKernelGGL(transpose_v, dim3(32, 16, 2), dim3(256), 0, stream,
                       qkvbf + 2ull * 4194304ull, vtbf);

    hipLaunchKernelGGL(attn_mfma, dim3(32, 16, 2), dim3(256), 0, stream,
                       qkvbf, qkvbf + 4194304ull, vtbf, srcb, tgtb, attbf);

    // O projection -> fp32 d_out; BN=64 -> 512 wgs (2/CU)
    hipLaunchKernelGGL((gemm_bt<0, 64>), dim3(16, 32), dim3(256), 0, stream,
                       attbf, wobf, bo, bo, bo, (unsigned short*)nullptr, (float*)d_out);

    (void)in_sizes; (void)n_in; (void)out_size; (void)ws_size;
}